// Round 12
// baseline (219.659 us; speedup 1.0000x reference)
//
#include <hip/hip_runtime.h>
#include <hip/hip_bf16.h>

#define H_ 64
#define FF_ 128
#define V_ 64
#define B_ 256
#define L_ 4096

typedef __attribute__((ext_vector_type(2))) float f32x2;
typedef __attribute__((ext_vector_type(4))) int i32x4;

__device__ __forceinline__ float wsum64(float x) {
  #pragma unroll
  for (int m = 32; m; m >>= 1) x += __shfl_xor(x, m, 64);
  return x;
}
__device__ __forceinline__ float readlane_f(float x, int lane) {
  return __int_as_float(__builtin_amdgcn_readlane(__float_as_int(x), lane));
}

// ---------------------------------------------------------------------------
// Kernel 1: per-token-id tables (verified round 3)
// ---------------------------------------------------------------------------
__global__ __launch_bounds__(64) void build_tables(
    const float* __restrict__ embed, const float* __restrict__ W1,
    const float* __restrict__ b1, const float* __restrict__ W2,
    const float* __restrict__ b2, const float* __restrict__ gamma,
    const float* __restrict__ beta, const float* __restrict__ Wk,
    const float* __restrict__ Wv, const float* __restrict__ Wq,
    float2* __restrict__ kv_table, float* __restrict__ q_table)
{
  const int tok = blockIdx.x;
  const int l = threadIdx.x;
  __shared__ float sh_h[H_];
  __shared__ float sh_a[FF_];
  __shared__ float sh_n[H_];

  float h = embed[tok * H_ + l];
  sh_h[l] = h;
  __syncthreads();

  float a0 = b1[l], a1 = b1[l + 64];
  #pragma unroll 8
  for (int j = 0; j < H_; ++j) {
    float hj = sh_h[j];
    a0 = fmaf(hj, W1[j * FF_ + l], a0);
    a1 = fmaf(hj, W1[j * FF_ + l + 64], a1);
  }
  sh_a[l]      = fmaxf(a0, 0.f);
  sh_a[l + 64] = fmaxf(a1, 0.f);
  __syncthreads();

  float x = h + b2[l];
  #pragma unroll 8
  for (int f = 0; f < FF_; ++f) x = fmaf(sh_a[f], W2[f * H_ + l], x);

  float mu = wsum64(x) * (1.0f / 64.0f);
  float d = x - mu;
  float var = wsum64(d * d) * (1.0f / 64.0f);
  float hn = d * rsqrtf(var + 1e-5f) * gamma[l] + beta[l];
  sh_n[l] = hn;
  __syncthreads();

  float k = 0.f, v = 0.f, q = 0.f;
  #pragma unroll 8
  for (int i = 0; i < H_; ++i) {
    float hi = sh_n[i];
    k = fmaf(hi, Wk[i * H_ + l], k);
    v = fmaf(hi, Wv[i * H_ + l], v);
    q = fmaf(hi, Wq[i * H_ + l], q);
  }
  float n2 = wsum64(k * k);
  float kn = k / fmaxf(sqrtf(n2), 1e-12f);
  kv_table[tok * H_ + l] = make_float2(kn, v);
  q_table[tok * H_ + l] = q;
}

// ---------------------------------------------------------------------------
// Kernel 2: Gram[a][j] = kn_a . kn_j
// ---------------------------------------------------------------------------
__global__ __launch_bounds__(64) void build_gram(
    const float2* __restrict__ kv_table, float* __restrict__ gram)
{
  const int arow = blockIdx.x;
  const int j = threadIdx.x;
  float s = 0.f;
  #pragma unroll 8
  for (int i = 0; i < H_; ++i)
    s = fmaf(kv_table[arow * H_ + i].x, kv_table[j * H_ + i].x, s);
  gram[arow * H_ + j] = s;
}

// ---------------------------------------------------------------------------
// Kernel 3: scan with precomputed per-chunk records.
// Record (32B, 8 dwords): [packed_tokens, m10, m20, m21, m30, m31, m32, pad]
// where c = M d (M = inverse of the chunk's unit-lower-triangular Gram
// system):  c0=d0; c1=m10*d0+d1; c2=m20*d0+m21*d1+d2; c3=m30*d0+m31*d1+m32*d2+d3
// EXEC per chunk: 4 PARALLEL readlanes of pre-chunk a + FMA trees.
// Pipeline (mod-4 slots): phase p issues rows(p+2) [4x ds_read_b64] then
// rec(p+4) [2x ds_read_b128]; LGKM(6) at top drains rows(p)+rec(p+2).
// Steady queue at phase p: [rows(p):4, rec(p+2):2, rows(p+1):4, rec(p+3):2].
// EXEC placed BEFORE RECLD so rec slot p%4 (m's) is read before overwrite.
// ---------------------------------------------------------------------------
#define DS64(dst, addr)  asm volatile("ds_read_b64 %0, %1"  : "=v"(dst) : "v"(addr))
#define DS128(dst, addr) asm volatile("ds_read_b128 %0, %1" : "=v"(dst) : "v"(addr))
#define LGKM(n) do { asm volatile("s_waitcnt lgkmcnt(" #n ")" ::: "memory"); \
                     __builtin_amdgcn_sched_barrier(0); } while (0)

#define PREP_DS(S) do { \
  unsigned pk = (unsigned)(rc##S.x); \
  DS64(rb##S##0, gv_base + (pk & 63u) * 512u); \
  DS64(rb##S##1, gv_base + ((pk >> 6) & 63u) * 512u); \
  DS64(rb##S##2, gv_base + ((pk >> 12) & 63u) * 512u); \
  DS64(rb##S##3, gv_base + ((pk >> 18) & 63u) * 512u); \
} while (0)

#define RECLD(S) do { \
  unsigned ar_ = (arec > rec_max) ? rec_max : arec; \
  DS128(rc##S, ar_); \
  DS128(rm##S, ar_ + 16u); \
  arec += 32u; \
} while (0)

#define PREP_SEL(S) do { \
  int ps_ = __builtin_amdgcn_readfirstlane(rc##S.x); \
  sl##S##0 = ps_ & 63; \
  sl##S##1 = (ps_ >> 6) & 63; \
  sl##S##2 = (ps_ >> 12) & 63; \
  sl##S##3 = (ps_ >> 18) & 63; \
} while (0)

#define EXEC(S) do { \
  float d0 = readlane_f(a, sl##S##0); \
  float d1 = readlane_f(a, sl##S##1); \
  float d2 = readlane_f(a, sl##S##2); \
  float d3 = readlane_f(a, sl##S##3); \
  float m10 = __int_as_float(rc##S.y); \
  float m20 = __int_as_float(rc##S.z); \
  float m21 = __int_as_float(rc##S.w); \
  float m30 = __int_as_float(rm##S.x); \
  float m31 = __int_as_float(rm##S.y); \
  float m32 = __int_as_float(rm##S.z); \
  float c0 = d0; \
  float c1 = fmaf(m10, d0, d1); \
  float c2 = fmaf(m20, d0, fmaf(m21, d1, d2)); \
  float c3 = fmaf(m30, d0, fmaf(m31, d1, fmaf(m32, d2, d3))); \
  float p01_ = fmaf(c1, (rb##S##1).x, c0 * (rb##S##0).x); \
  float p23_ = fmaf(c3, (rb##S##3).x, c2 * (rb##S##2).x); \
  a = a - p01_ - p23_; \
  r = fmaf(c0, (rb##S##0).y, r); \
  r = fmaf(c1, (rb##S##1).y, r); \
  r = fmaf(c2, (rb##S##2).y, r); \
  r = fmaf(c3, (rb##S##3).y, r); \
} while (0)

#define PHASE(E, P2) do { \
  LGKM(6); \
  PREP_DS(P2); \
  EXEC(E); \
  RECLD(E); \
  PREP_SEL(P2); \
} while (0)

__global__ __launch_bounds__(64) void scan_kernel(
    const int* __restrict__ seq, const float2* __restrict__ kv_table,
    const float* __restrict__ q_table, const float* __restrict__ gram,
    const float* __restrict__ Wr, const float* __restrict__ br,
    const float* __restrict__ Wo, const float* __restrict__ bo,
    float* __restrict__ out)
{
  const int b = blockIdx.x, l = threadIdx.x;
  __shared__ float kn_s[64 * 65];                 // padded kn rows (a-init)
  __shared__ __align__(16) float2 gv_s[64 * 64];  // (gram, v) fused rows, 32 KB
  __shared__ __align__(16) int rec_s[1023 * 8];   // 32 KB chunk records
  __shared__ float qs[64], sh_r[64], sh_rr[64];

  // stage tables: kn (padded) + fused (gram, v)
  for (int idx = l * 2; idx < 4096; idx += 128) {
    float4 kv2 = *reinterpret_cast<const float4*>(&kv_table[idx]); // 2 float2
    float2 g2 = *reinterpret_cast<const float2*>(&gram[idx]);
    int row = idx >> 6, col = idx & 63;
    kn_s[row * 65 + col] = kv2.x;
    kn_s[row * 65 + col + 1] = kv2.z;
    gv_s[idx] = make_float2(g2.x, kv2.y);
    gv_s[idx + 1] = make_float2(g2.y, kv2.w);
  }
  __syncthreads();

  // build per-chunk records (chunk rcd covers t = 4091-4*rcd .. 4088-4*rcd)
  for (int rcd = l; rcd < 1023; rcd += 64) {
    const int4 tv = *reinterpret_cast<const int4*>(seq + b * L_ + (4088 - 4 * rcd));
    int s0 = tv.w, s1 = tv.z, s2 = tv.y, s3 = tv.x;  // descending t order
    float g10 = gv_s[s0 * 64 + s1].x;
    float g20 = gv_s[s0 * 64 + s2].x;
    float g21 = gv_s[s1 * 64 + s2].x;
    float g30 = gv_s[s0 * 64 + s3].x;
    float g31 = gv_s[s1 * 64 + s3].x;
    float g32 = gv_s[s2 * 64 + s3].x;
    float m10 = -g10;
    float m21 = -g21;
    float m20 = -g20 - g21 * m10;
    float m32 = -g32;
    float m31 = -g31 - g32 * m21;
    float m30 = -g30 - g31 * m10 - g32 * m20;
    int* rp = rec_s + rcd * 8;
    rp[0] = s0 | (s1 << 6) | (s2 << 12) | (s3 << 18);
    rp[1] = __float_as_int(m10);
    rp[2] = __float_as_int(m20);
    rp[3] = __float_as_int(m21);
    rp[4] = __float_as_int(m30);
    rp[5] = __float_as_int(m31);
    rp[6] = __float_as_int(m32);
    rp[7] = 0;
  }
  __syncthreads();

  const int tq = seq[b * L_ + 4095];
  qs[l] = q_table[tq * 64 + l];
  __syncthreads();

  // a_l = kn_vocab[l] . q
  float a = 0.f;
  #pragma unroll 8
  for (int i = 0; i < 64; ++i) a = fmaf(kn_s[l * 65 + i], qs[i], a);
  float r = 0.f;

  // 3 singles: t = 4094, 4093, 4092 (plain C)
  const float2* gvl = gv_s + l;
  #pragma unroll
  for (int t = 4094; t >= 4092; --t) {
    int s0 = seq[b * L_ + t];
    float2 g = gvl[s0 * 64];
    float c0 = readlane_f(a, s0);
    a = fmaf(-c0, g.x, a);
    r = fmaf(c0, g.y, r);
  }

  // ---- asm pipeline over 1023 chunks ----
  unsigned gv_base  = (unsigned)(size_t)gv_s + (unsigned)l * 8u;
  unsigned rec_base = (unsigned)(size_t)rec_s;
  unsigned rec_max  = rec_base + 32u * 1022u;
  unsigned arec = rec_base;
  i32x4 rc0, rc1, rc2, rc3, rm0, rm1, rm2, rm3;
  f32x2 rb00, rb01, rb02, rb03, rb10, rb11, rb12, rb13,
        rb20, rb21, rb22, rb23, rb30, rb31, rb32, rb33;
  int sl00, sl01, sl02, sl03, sl10, sl11, sl12, sl13,
      sl20, sl21, sl22, sl23, sl30, sl31, sl32, sl33;

  // prologue -> steady-state queue [rows0:4, rec2:2, rows1:4, rec3:2]
  RECLD(0);            // rec 0
  RECLD(1);            // rec 1
  LGKM(0);
  PREP_DS(0);          // rows chunk 0
  RECLD(2);            // rec 2
  PREP_DS(1);          // rows chunk 1
  RECLD(3);            // rec 3
  PREP_SEL(0);
  PREP_SEL(1);

  #pragma unroll 1
  for (int it = 0; it < 255; ++it) {   // phases 0..1019
    PHASE(0, 2);
    PHASE(1, 3);
    PHASE(2, 0);
    PHASE(3, 1);
  }
  PHASE(0, 2);   // phase 1020
  PHASE(1, 3);   // phase 1021
  PHASE(2, 0);   // phase 1022  (chunks 0..1022 executed; 3 + 1023*4 = 4095)
  LGKM(0);       // drain stray prefetches before tail

  // tail: out = (r @ Wr + br) @ Wo + bo
  sh_r[l] = r;
  __syncthreads();
  float rr = br[l];
  #pragma unroll 8
  for (int i = 0; i < 64; ++i) rr = fmaf(sh_r[i], Wr[i * 64 + l], rr);
  sh_rr[l] = rr;
  __syncthreads();
  float o = bo[l];
  #pragma unroll 8
  for (int j = 0; j < 64; ++j) o = fmaf(sh_rr[j], Wo[j * 64 + l], o);
  out[b * V_ + l] = o;
}

extern "C" void kernel_launch(void* const* d_in, const int* in_sizes, int n_in,
                              void* d_out, int out_size, void* d_ws, size_t ws_size,
                              hipStream_t stream) {
  const int*   seq   = (const int*)  d_in[0];
  const float* embed = (const float*)d_in[1];
  const float* W1    = (const float*)d_in[2];
  const float* b1    = (const float*)d_in[3];
  const float* W2    = (const float*)d_in[4];
  const float* b2    = (const float*)d_in[5];
  const float* gamma = (const float*)d_in[6];
  const float* beta  = (const float*)d_in[7];
  const float* Wk    = (const float*)d_in[8];
  const float* Wv    = (const float*)d_in[9];
  const float* Wq    = (const float*)d_in[10];
  const float* Wr    = (const float*)d_in[11];
  const float* br    = (const float*)d_in[12];
  const float* Wo    = (const float*)d_in[13];
  const float* bo    = (const float*)d_in[14];
  float* out = (float*)d_out;

  float2* kv_table = (float2*)d_ws;                     // 32 KB
  float*  q_table  = (float*)((char*)d_ws + 32 * 1024); // 16 KB
  float*  gram     = (float*)((char*)d_ws + 48 * 1024); // 16 KB

  build_tables<<<V_, 64, 0, stream>>>(embed, W1, b1, W2, b2, gamma, beta,
                                      Wk, Wv, Wq, kv_table, q_table);
  build_gram<<<V_, 64, 0, stream>>>(kv_table, gram);
  scan_kernel<<<B_, 64, 0, stream>>>(seq, kv_table, q_table, gram,
                                     Wr, br, Wo, bo, out);
}